// Round 3
// baseline (173.392 us; speedup 1.0000x reference)
//
#include <hip/hip_runtime.h>
#include <math.h>

#define B    256
#define I    1152
#define O    10
#define DIN  8
#define DOUT 16
#define OE   160          // O*DOUT
#define XROW 9216         // I*DIN (also K of the s-GEMM, and M of the g-GEMM)
#define WROW 1280         // O*DIN*DOUT (= OE*DIN, Wt/G row length)
#define PSPLIT 72         // split-K partials
#define CHUNK  16         // i per spart block
#define SI     8          // i per staging round (K-window 64)

#define WPREP_BLOCKS 720              // I*OE/256
#define XT_BLOCKS    1152             // (9216/64) * (256/32)
#define PREP_BLOCKS  (WPREP_BLOCKS + XT_BLOCKS)

typedef __attribute__((ext_vector_type(8))) short short8;
typedef __attribute__((ext_vector_type(4))) float floatx4;

__device__ __forceinline__ unsigned short f2bf(float f) {
    unsigned u = __builtin_bit_cast(unsigned, f);
    u += 0x7fffu + ((u >> 16) & 1u);          // RNE
    return (unsigned short)(u >> 16);
}
__device__ __forceinline__ float bf2f(unsigned short h) {
    unsigned u = ((unsigned)h) << 16;
    return __builtin_bit_cast(float, u);
}

// 8 consecutive fp32 -> bf16 hi/lo pair (RNE), in registers.
__device__ __forceinline__ void split8(const float* __restrict__ xp,
                                       short8& h8, short8& l8)
{
    float4 v0 = *(const float4*)xp;
    float4 v1 = *(const float4*)(xp + 4);
    float v[8] = {v0.x, v0.y, v0.z, v0.w, v1.x, v1.y, v1.z, v1.w};
#pragma unroll
    for (int d = 0; d < 8; ++d) {
        unsigned short h = f2bf(v[d]);
        h8[d] = (short)h;
        l8[d] = (short)f2bf(v[d] - bf2f(h));
    }
}

// ---------------------------------------------------------------------------
// PREP (one-time, fused):
//  blocks [0, WPREP):        W -> Wt[i][oe][d] fp32 (d-contiguous).
//  blocks [WPREP, +XT):      x -> xTh/xTl[(i*8+d)][b] bf16 hi/lo (b-contiguous)
//                            = the A-operand of the agreement g-GEMM.
// ---------------------------------------------------------------------------
__global__ __launch_bounds__(256) void prep_kernel(
    const float* __restrict__ x, const float* __restrict__ W,
    float* __restrict__ Wt,
    unsigned short* __restrict__ xTh, unsigned short* __restrict__ xTl)
{
    int blk = blockIdx.x;
    int t   = threadIdx.x;
    if (blk < WPREP_BLOCKS) {
        int g  = blk * 256 + t;                   // (i, oe) pair
        int i  = g / OE;
        int oe = g - i * OE;
        int o  = oe >> 4;
        int e  = oe & 15;
        const float* wp = W + (size_t)i * WROW + o * (DIN * DOUT) + e;
        float4 a, b;
        a.x = wp[0 * DOUT]; a.y = wp[1 * DOUT]; a.z = wp[2 * DOUT]; a.w = wp[3 * DOUT];
        b.x = wp[4 * DOUT]; b.y = wp[5 * DOUT]; b.z = wp[6 * DOUT]; b.w = wp[7 * DOUT];
        float4* dst = (float4*)(Wt + (size_t)g * 8);
        dst[0] = a;
        dst[1] = b;
    } else {
        int g2  = blk - WPREP_BLOCKS;             // 0..1151
        int idb = g2 % 144;
        int bb  = g2 / 144;
        int id  = idb * 64 + (t & 63);            // (i,d) flat row, lanes consecutive
        int b0  = bb * 32 + (t >> 6) * 8;         // 8 batch elems per thread
        float v[8];
#pragma unroll
        for (int j = 0; j < 8; ++j)               // coalesced: lanes vary id
            v[j] = x[(size_t)(b0 + j) * XROW + id];
        short8 h8, l8;
#pragma unroll
        for (int j = 0; j < 8; ++j) {
            unsigned short h = f2bf(v[j]);
            h8[j] = (short)h;
            l8[j] = (short)f2bf(v[j] - bf2f(h));
        }
        *(short8*)(xTh + (size_t)id * B + b0) = h8;
        *(short8*)(xTl + (size_t)id * B + b0) = l8;
    }
}

// ---------------------------------------------------------------------------
// SPART v6: MFMA bf16 hi/lo split-K GEMM + fused routing prologue.
// phase 0: c = 0.1 uniform (iteration 1).
// phase 1: b = agree(G)          (iteration 2; persists blog, no reads)
// phase 2: b = blog + agree(G)   (iteration 3; reads blog, no writes)
// Prologue (phase>0): threads 0..159 compute agree[i,o] = sum_{e,d}
// Wt[i][oe][d]*G[i][oe][d] (both 512B-contiguous per (i,o)), b-update,
// then 16 threads do the 10-wide softmax -> cL in LDS. Replaces the old
// agree_kernel (whose per-b LDS broadcast reads cost ~33us/launch).
// GEMM body identical to proven v5.
// ---------------------------------------------------------------------------
__global__ __launch_bounds__(256) void spart_mfma(
    const float* __restrict__ x, const float* __restrict__ Wt,
    const float* __restrict__ G, float* __restrict__ blog,
    float* __restrict__ sp, int phase)
{
    __shared__ unsigned short Wh[80 * 64], Wl[80 * 64];    // [oe-local][k-window]
    __shared__ float brow_s[16][10];
    __shared__ float cL[16][10];

    int bid = blockIdx.x;
    int ic  = bid >> 2;
    int mb  = (bid >> 1) & 1;
    int nb  = bid & 1;
    int b0  = mb * 128;
    int oe0 = nb * 80;
    int i0  = ic * CHUNK;

    int t    = threadIdx.x;
    int w    = t >> 6;
    int lane = t & 63;
    int l15  = lane & 15;
    int q    = lane >> 4;

    // ---- routing prologue: agree + b-update + softmax -> cL ----
    if (phase) {
        if (t < 160) {
            int iL = t / 10;
            int o  = t - iL * 10;
            int i  = i0 + iL;
            const float4* wp = (const float4*)(Wt + (size_t)i * WROW + o * 128);
            const float4* gp = (const float4*)(G  + (size_t)i * WROW + o * 128);
            float sacc = 0.f;
#pragma unroll
            for (int j = 0; j < 32; ++j) {
                float4 wv = wp[j], gv = gp[j];
                sacc = fmaf(wv.x, gv.x, sacc);
                sacc = fmaf(wv.y, gv.y, sacc);
                sacc = fmaf(wv.z, gv.z, sacc);
                sacc = fmaf(wv.w, gv.w, sacc);
            }
            float bo = sacc * (1.f / (float)B);
            if (phase == 2) bo += blog[i * O + o];          // read-only pass
            else if ((bid & 3) == 0) blog[i * O + o] = bo;  // persist once
            brow_s[iL][o] = bo;
        }
        __syncthreads();
        if (t < 16) {
            float m = brow_s[t][0];
#pragma unroll
            for (int o = 1; o < O; ++o) m = fmaxf(m, brow_s[t][o]);
            float ex[O];
            float sum = 0.f;
#pragma unroll
            for (int o = 0; o < O; ++o) { ex[o] = __expf(brow_s[t][o] - m); sum += ex[o]; }
            float inv = 1.f / sum;
#pragma unroll
            for (int o = 0; o < O; ++o) cL[t][o] = ex[o] * inv;
        }
        __syncthreads();
    }

    floatx4 acc[2][5];
#pragma unroll
    for (int mt = 0; mt < 2; ++mt)
#pragma unroll
        for (int nt = 0; nt < 5; ++nt) acc[mt][nt] = (floatx4)(0.f);

#pragma unroll
    for (int round = 0; round < CHUNK / SI; ++round) {
        int si0 = i0 + round * SI;
        if (round) __syncthreads();

        // ---- X fragments: direct global fp32 loads + in-register split ----
        short8 ah[2][2], al[2][2];                // [ks][mt]
#pragma unroll
        for (int ks = 0; ks < 2; ++ks)
#pragma unroll
            for (int mt = 0; mt < 2; ++mt) {
                const float* xp = x + (size_t)(b0 + w * 32 + mt * 16 + l15) * XROW
                                + (size_t)si0 * 8 + (ks << 5) + (q << 3);
                split8(xp, ah[ks][mt], al[ks][mt]);
            }

        // ---- stage W: coalesced loads from Wt, scale by c, split hi/lo ----
#pragma unroll
        for (int r = 0; r < 3; ++r) {
            int p = t + 256 * r;                  // (oe-local, i-local) pair
            if (p < 640) {
                int oeL = p % 80;
                int iL  = p / 80;                 // 0..7
                int o   = (oe0 + oeL) >> 4;
                const float* wp = Wt + ((size_t)(si0 + iL) * OE + oe0 + oeL) * 8;
                float cv = phase ? cL[round * SI + iL][o] : 0.1f;
                float4 w0 = *(const float4*)wp;
                float4 w1 = *(const float4*)(wp + 4);
                float wv[8] = {w0.x, w0.y, w0.z, w0.w, w1.x, w1.y, w1.z, w1.w};
                short8 hv, lv;
#pragma unroll
                for (int d = 0; d < 8; ++d) {
                    float s = wv[d] * cv;
                    unsigned short h = f2bf(s);
                    hv[d] = (short)h;
                    lv[d] = (short)f2bf(s - bf2f(h));
                }
                int off = oeL * 64 + ((iL ^ (oeL & 7)) << 3);
                *(short8*)(Wh + off) = hv;
                *(short8*)(Wl + off) = lv;
            }
        }
        __syncthreads();

        // ---- 2 K-steps of 32 over the staged window ----
#pragma unroll
        for (int ks = 0; ks < 2; ++ks) {
#pragma unroll
            for (int nt = 0; nt < 5; ++nt) {
                int rn  = nt * 16 + l15;
                int off = rn * 64 + ((((ks << 2) + q) ^ (rn & 7)) << 3);
                short8 bh = *(const short8*)(Wh + off);
                short8 bl = *(const short8*)(Wl + off);
#pragma unroll
                for (int mt = 0; mt < 2; ++mt) {
                    acc[mt][nt] = __builtin_amdgcn_mfma_f32_16x16x32_bf16(ah[ks][mt], bh, acc[mt][nt], 0, 0, 0);
                    acc[mt][nt] = __builtin_amdgcn_mfma_f32_16x16x32_bf16(ah[ks][mt], bl, acc[mt][nt], 0, 0, 0);
                    acc[mt][nt] = __builtin_amdgcn_mfma_f32_16x16x32_bf16(al[ks][mt], bh, acc[mt][nt], 0, 0, 0);
                }
            }
        }
    }

    // ---- epilogue: C/D layout col=lane&15, row=(lane>>4)*4+reg (m89/m91) ----
    float* base = sp + (size_t)ic * (B * OE);
#pragma unroll
    for (int mt = 0; mt < 2; ++mt) {
        int row0 = b0 + w * 32 + mt * 16 + q * 4;
#pragma unroll
        for (int nt = 0; nt < 5; ++nt) {
            int col = oe0 + nt * 16 + l15;
#pragma unroll
            for (int reg = 0; reg < 4; ++reg)
                base[(row0 + reg) * OE + col] = acc[mt][nt][reg];
        }
    }
}

// ---------------------------------------------------------------------------
// VRED: sum P partials + squash; iters 0,1 -> write v as bf16 hi/lo
// TRANSPOSED [oe][b] (the B-operand of the g-GEMM); iter 2 -> final out.
// ---------------------------------------------------------------------------
__global__ __launch_bounds__(256) void vred_kernel(
    const float* __restrict__ sp, float* __restrict__ dst,
    unsigned short* __restrict__ vhT, unsigned short* __restrict__ vlT, int last)
{
    int g = blockIdx.x * 256 + threadIdx.x;     // [b][o][e] flat
    float s = 0.f;
#pragma unroll 8
    for (int ic = 0; ic < PSPLIT; ++ic) s += sp[(size_t)ic * (B * OE) + g];

    float ss = s * s;
    ss += __shfl_xor(ss, 1, 16);
    ss += __shfl_xor(ss, 2, 16);
    ss += __shfl_xor(ss, 4, 16);
    ss += __shfl_xor(ss, 8, 16);
    float f = sqrtf(ss) / (1.f + ss);           // squash factor
    float val = s * f;

    if (last) {
        dst[g] = val;
    } else {
        int b  = g / OE;
        int oe = g - b * OE;
        unsigned short h = f2bf(val);
        vhT[oe * B + b] = h;
        vlT[oe * B + b] = f2bf(val - bf2f(h));
    }
}

// ---------------------------------------------------------------------------
// GGEMM: G[(i,d)][oe] = sum_b xT[(i,d)][b] * v[b][oe]   (M=9216,N=160,K=256)
// Same MFMA hi/lo structure as spart; output scattered to G[i][oe][d]
// (d-contiguous float4, matching Wt) so the spart prologue reads 512B runs.
// grid = 72 m-blocks x 2 n-halves = 144; block = 4 waves, wave 32M x 80N.
// ---------------------------------------------------------------------------
__global__ __launch_bounds__(256) void ggemm_kernel(
    const unsigned short* __restrict__ xTh, const unsigned short* __restrict__ xTl,
    const unsigned short* __restrict__ vhT, const unsigned short* __restrict__ vlT,
    float* __restrict__ G)
{
    __shared__ unsigned short Vh[80 * 64], Vl[80 * 64];    // [oe-local][b-window]

    int bid = blockIdx.x;
    int m0  = (bid >> 1) * 128;
    int nb  = bid & 1;
    int oe0 = nb * 80;

    int t    = threadIdx.x;
    int w    = t >> 6;
    int lane = t & 63;
    int l15  = lane & 15;
    int q    = lane >> 4;

    floatx4 acc[2][5];
#pragma unroll
    for (int mt = 0; mt < 2; ++mt)
#pragma unroll
        for (int nt = 0; nt < 5; ++nt) acc[mt][nt] = (floatx4)(0.f);

#pragma unroll
    for (int win = 0; win < 4; ++win) {
        int k0 = win * 64;
        if (win) __syncthreads();

        // ---- stage V window [80 oe][64 b], XOR-swizzled 16B chunks ----
#pragma unroll
        for (int r = 0; r < 3; ++r) {
            int p = t + 256 * r;
            if (p < 640) {
                int row = p >> 3;
                int ch  = p & 7;
                int off = row * 64 + ((ch ^ (row & 7)) << 3);
                size_t gsrc = (size_t)(oe0 + row) * B + k0 + (ch << 3);
                *(short8*)(Vh + off) = *(const short8*)(vhT + gsrc);
                *(short8*)(Vl + off) = *(const short8*)(vlT + gsrc);
            }
        }
        __syncthreads();

        // ---- A fragments direct from xT (b-contiguous rows) ----
        short8 ah[2][2], al[2][2];
#pragma unroll
        for (int ks = 0; ks < 2; ++ks)
#pragma unroll
            for (int mt = 0; mt < 2; ++mt) {
                size_t ga = (size_t)(m0 + w * 32 + mt * 16 + l15) * B
                          + k0 + (ks << 5) + (q << 3);
                ah[ks][mt] = *(const short8*)(xTh + ga);
                al[ks][mt] = *(const short8*)(xTl + ga);
            }

#pragma unroll
        for (int ks = 0; ks < 2; ++ks) {
#pragma unroll
            for (int nt = 0; nt < 5; ++nt) {
                int rn  = nt * 16 + l15;
                int off = rn * 64 + ((((ks << 2) + q) ^ (rn & 7)) << 3);
                short8 bh = *(const short8*)(Vh + off);
                short8 bl = *(const short8*)(Vl + off);
#pragma unroll
                for (int mt = 0; mt < 2; ++mt) {
                    acc[mt][nt] = __builtin_amdgcn_mfma_f32_16x16x32_bf16(ah[ks][mt], bh, acc[mt][nt], 0, 0, 0);
                    acc[mt][nt] = __builtin_amdgcn_mfma_f32_16x16x32_bf16(ah[ks][mt], bl, acc[mt][nt], 0, 0, 0);
                    acc[mt][nt] = __builtin_amdgcn_mfma_f32_16x16x32_bf16(al[ks][mt], bh, acc[mt][nt], 0, 0, 0);
                }
            }
        }
    }

    // ---- epilogue: rows rb..rb+3 = same i, 4 consecutive d -> float4 ----
#pragma unroll
    for (int mt = 0; mt < 2; ++mt) {
        int rb = m0 + w * 32 + mt * 16 + q * 4;
        int i  = rb >> 3;
        int d0 = rb & 7;                          // 0 or 4
#pragma unroll
        for (int nt = 0; nt < 5; ++nt) {
            int col = oe0 + nt * 16 + l15;
            *(floatx4*)(G + (size_t)i * WROW + col * 8 + d0) = acc[mt][nt];
        }
    }
}

// ---------------------------------------------------------------------------
extern "C" void kernel_launch(void* const* d_in, const int* in_sizes, int n_in,
                              void* d_out, int out_size, void* d_ws, size_t ws_size,
                              hipStream_t stream)
{
    const float* x = (const float*)d_in[0];   // [256,1152,8]
    const float* W = (const float*)d_in[1];   // [1152,10,8,16]
    float* out = (float*)d_out;               // [256,10,16,1] flat = 40960

    // ws (floats then ushorts): blog | Wt 5.9MB | G 5.9MB | sp 11.8MB |
    //                           xTh 4.7MB | xTl 4.7MB | vhT | vlT   (~33MB)
    float* blog = (float*)d_ws;
    float* Wt   = blog + I * O;
    float* G    = Wt + (size_t)I * OE * DIN;
    float* sp   = G  + (size_t)I * OE * DIN;
    unsigned short* xTh = (unsigned short*)(sp + (size_t)PSPLIT * B * OE);
    unsigned short* xTl = xTh + (size_t)XROW * B;
    unsigned short* vhT = xTl + (size_t)XROW * B;
    unsigned short* vlT = vhT + (size_t)B * OE;

    // ---- one-time: W transpose + x transpose/split (iteration-invariant) ----
    prep_kernel<<<PREP_BLOCKS, 256, 0, stream>>>(x, W, Wt, xTh, xTl);

    dim3 gs(4 * PSPLIT), bs(256);
    // ---- iteration 1 (c uniform 0.1) ----
    spart_mfma<<<gs, bs, 0, stream>>>(x, Wt, G, blog, sp, 0);
    vred_kernel<<<160, 256, 0, stream>>>(sp, out, vhT, vlT, 0);
    ggemm_kernel<<<144, 256, 0, stream>>>(xTh, xTl, vhT, vlT, G);
    // ---- iteration 2 (b = agree; persists blog) ----
    spart_mfma<<<gs, bs, 0, stream>>>(x, Wt, G, blog, sp, 1);
    vred_kernel<<<160, 256, 0, stream>>>(sp, out, vhT, vlT, 0);
    ggemm_kernel<<<144, 256, 0, stream>>>(xTh, xTl, vhT, vlT, G);
    // ---- iteration 3 (b = blog + agree; squash straight into d_out) ----
    spart_mfma<<<gs, bs, 0, stream>>>(x, Wt, G, blog, sp, 2);
    vred_kernel<<<160, 256, 0, stream>>>(sp, out, vhT, vlT, 1);
}